// Round 3
// baseline (713.557 us; speedup 1.0000x reference)
//
#include <hip/hip_runtime.h>
#include <math.h>

#define B_ 8
#define N_ 1024
#define C_ 320
#define H_ 5
#define D_ 64
#define M_ (B_*N_)
#define TM 16

typedef unsigned short ushort_t;
typedef __attribute__((ext_vector_type(8))) short bf16x8;
typedef __attribute__((ext_vector_type(4))) float f32x4;

struct Gauss {
  float u[H_][7];   // 1D gaussian (normalized)
  float au[H_][7];  // alpha * u
};

// fp32 -> bf16 RNE (manual, version-stable)
__device__ __forceinline__ ushort_t f2b(float f) {
  union { float f; unsigned u; } c; c.f = f;
  unsigned r = c.u + 0x7fffu + ((c.u >> 16) & 1u);
  return (ushort_t)(r >> 16);
}
__device__ __forceinline__ float b2f(ushort_t u) {
  union { float f; unsigned u; } c; c.u = ((unsigned)u) << 16;
  return c.f;
}

// ---------------- LayerNorm: one wave per row ----------------
__global__ __launch_bounds__(64) void ln_kernel(const float* __restrict__ x,
    const float* __restrict__ gamma, const float* __restrict__ beta,
    float* __restrict__ xn) {
  int row = blockIdx.x;
  int lane = threadIdx.x;
  const float* xr = x + (long)row * C_;
  float vals[5];
  float s = 0.f, ss = 0.f;
#pragma unroll
  for (int j = 0; j < 5; ++j) {
    float vv = xr[lane + 64*j];
    vals[j] = vv; s += vv; ss += vv*vv;
  }
#pragma unroll
  for (int o = 32; o > 0; o >>= 1) {
    s  += __shfl_xor(s, o, 64);
    ss += __shfl_xor(ss, o, 64);
  }
  float mean = s * (1.0f/C_);
  float var  = ss * (1.0f/C_) - mean*mean;
  float rstd = rsqrtf(var + 1e-5f);
  float* outr = xn + (long)row * C_;
#pragma unroll
  for (int j = 0; j < 5; ++j) {
    int c = lane + 64*j;
    outr[c] = (vals[j]-mean)*rstd*gamma[c] + beta[c];
  }
}

// ---------------- QKV GEMM (8192x320 @ 320x960^T) + scatter ----------------
// q (pre-scaled by d^-0.5) and k stored bf16 in (B,H,N,d); v TRANSPOSED bf16 vt[bh][d][n]
__global__ __launch_bounds__(256) void qkv_kernel(const float* __restrict__ xn,
    const float* __restrict__ w, const float* __restrict__ bias,
    ushort_t* __restrict__ q, ushort_t* __restrict__ k, ushort_t* __restrict__ vt) {
  __shared__ float As[16][68];
  __shared__ float Bs[16][68];
  int j0 = blockIdx.x * 64;
  int m0 = blockIdx.y * 64;
  int tid = threadIdx.x;
  int tx = tid & 15, ty = tid >> 4;
  int lr = tid >> 2;
  int lc = (tid & 3) << 2;
  float acc[4][4] = {};
  for (int kk = 0; kk < C_; kk += 16) {
    float4 a4 = *(const float4*)(xn + (long)(m0+lr)*C_ + kk + lc);
    float4 b4 = *(const float4*)(w  + (long)(j0+lr)*C_ + kk + lc);
    As[lc+0][lr]=a4.x; As[lc+1][lr]=a4.y; As[lc+2][lr]=a4.z; As[lc+3][lr]=a4.w;
    Bs[lc+0][lr]=b4.x; Bs[lc+1][lr]=b4.y; Bs[lc+2][lr]=b4.z; Bs[lc+3][lr]=b4.w;
    __syncthreads();
#pragma unroll
    for (int p = 0; p < 16; ++p) {
      float4 av = *(const float4*)&As[p][ty<<2];
      float4 bv = *(const float4*)&Bs[p][tx<<2];
      float aa[4] = {av.x,av.y,av.z,av.w};
      float bb[4] = {bv.x,bv.y,bv.z,bv.w};
#pragma unroll
      for (int i=0;i<4;++i)
#pragma unroll
        for (int j=0;j<4;++j) acc[i][j] += aa[i]*bb[j];
    }
    __syncthreads();
  }
#pragma unroll
  for (int i=0;i<4;++i) {
    int m = m0 + (ty<<2) + i;
    int bb2 = m >> 10, n = m & (N_-1);
#pragma unroll
    for (int j=0;j<4;++j) {
      int col = j0 + (tx<<2) + j;
      float val = acc[i][j] + bias[col];
      int three = col / 320;
      int rem = col - three*320;
      int h = rem >> 6, dd = rem & 63;
      if (three == 0) {
        q[(((long)bb2*H_ + h)*N_ + n)*D_ + dd] = f2b(val * 0.125f);  // fold d^-0.5
      } else if (three == 1) {
        k[(((long)bb2*H_ + h)*N_ + n)*D_ + dd] = f2b(val);
      } else {
        vt[(((long)bb2*H_ + h)*D_ + dd)*N_ + n] = f2b(val);
      }
    }
  }
}

// ---------------- QK^T per (b,h) via MFMA bf16: 128x128 tile / block ----------------
__global__ __launch_bounds__(256, 4) void qk_kernel(const ushort_t* __restrict__ q,
    const ushort_t* __restrict__ kmat, ushort_t* __restrict__ attn) {
  __shared__ __align__(16) ushort_t Qs[128][72];  // +8 pad: 2-way bank alias (free)
  __shared__ __align__(16) ushort_t Ks[128][72];
  int bh = blockIdx.z;
  int m0 = blockIdx.x * 128;   // query rows
  int n0 = blockIdx.y * 128;   // key cols
  int tid = threadIdx.x;
  int lane = tid & 63, wv = tid >> 6;
  int l16 = lane & 15, qd = lane >> 4;
  const ushort_t* qb = q    + ((long)bh*N_ + m0)*D_;
  const ushort_t* kb = kmat + ((long)bh*N_ + n0)*D_;
#pragma unroll
  for (int i = 0; i < 4; ++i) {
    int chunk = tid + 256*i;            // 1024 chunks of 8 bf16
    int row = chunk >> 3, c8 = (chunk & 7) << 3;
    *(uint4*)&Qs[row][c8] = *(const uint4*)(qb + (long)row*D_ + c8);
    *(uint4*)&Ks[row][c8] = *(const uint4*)(kb + (long)row*D_ + c8);
  }
  __syncthreads();
  f32x4 acc[2][8];
#pragma unroll
  for (int i=0;i<2;++i)
#pragma unroll
    for (int j=0;j<8;++j) acc[i][j] = (f32x4){0.f,0.f,0.f,0.f};
#pragma unroll
  for (int ks = 0; ks < 2; ++ks) {
    int k0 = ks*32 + qd*8;
    bf16x8 a0 = *(const bf16x8*)&Qs[wv*32 + l16][k0];
    bf16x8 a1 = *(const bf16x8*)&Qs[wv*32 + 16 + l16][k0];
#pragma unroll
    for (int ct = 0; ct < 8; ++ct) {
      bf16x8 b = *(const bf16x8*)&Ks[ct*16 + l16][k0];
      acc[0][ct] = __builtin_amdgcn_mfma_f32_16x16x32_bf16(a0, b, acc[0][ct], 0,0,0);
      acc[1][ct] = __builtin_amdgcn_mfma_f32_16x16x32_bf16(a1, b, acc[1][ct], 0,0,0);
    }
  }
  ushort_t* ob = attn + ((long)bh*N_ + m0 + wv*32)*N_ + n0;
#pragma unroll
  for (int rt = 0; rt < 2; ++rt)
#pragma unroll
    for (int r = 0; r < 4; ++r) {
      long rowoff = (long)(rt*16 + qd*4 + r)*N_;
#pragma unroll
      for (int ct = 0; ct < 8; ++ct)
        ob[rowoff + ct*16 + l16] = f2b(acc[rt][ct][r]);
    }
}

// ------- Fused separable blur + softmax + MFMA PV (spill-proof delay-line) -------
__global__ __launch_bounds__(1024, 8) void bsp_kernel(
    const ushort_t* __restrict__ attn, const ushort_t* __restrict__ vt,
    float* __restrict__ ao, Gauss gw) {
  __shared__ ushort_t P[TM][1032];    // bf16 exp(logits); +8 pad for A-frag banking
  __shared__ float scratch[4096];     // [0..2047] dbuf rowbuf | [2048..2559] reductions | PV partials
  __shared__ float bmax[TM], bsum[TM];

  int bh = blockIdx.y;
  int h = bh % H_;
  int n0 = blockIdx.x * TM;
  int tid = threadIdx.x;
  int m = tid;
  int lane = tid & 63, wv = tid >> 6;
  const ushort_t* ab = attn + (long)bh*N_*N_;

  // block-uniform coefficients -> SGPRs
  float u0 = gw.u[h][0], u1 = gw.u[h][1], u2 = gw.u[h][2], u3 = gw.u[h][3],
        u4 = gw.u[h][4], u5 = gw.u[h][5], u6 = gw.u[h][6];
  float au0 = gw.au[h][0], au1 = gw.au[h][1], au2 = gw.au[h][2], au3 = gw.au[h][3],
        au4 = gw.au[h][4], au5 = gw.au[h][5], au6 = gw.au[h][6];

  // column-neighbor indices with reflect (named scalars: no dynamic indexing)
  int nb0 = m >= 3 ? m-3 : 3-m;
  int nb1 = m >= 2 ? m-2 : 2-m;
  int nb2 = m >= 1 ? m-1 : 1-m;
  int nb3 = m;
  int nb4 = m+1 <= N_-1 ? m+1 : 2*(N_-1)-(m+1);
  int nb5 = m+2 <= N_-1 ? m+2 : 2*(N_-1)-(m+2);
  int nb6 = m+3 <= N_-1 ? m+3 : 2*(N_-1)-(m+3);

  float rbw0=0,rbw1=0,rbw2=0,rbw3=0,rbw4=0,rbw5=0,rbw6=0;  // rb delay line
  float vd0=0,vd1=0,vd2=0,vd3=0;                            // raw-val delay line
  float lg[16];
  float vcur, vnxt = 0.f;
  {
    int p = n0 - 3;
    int rr = p < 0 ? -p : p;
    vcur = b2f(ab[(long)rr*N_ + m]);
  }

#define BSP_STEP(s, EMIT) \
  { \
    if ((s) < 21) { \
      int pn = n0 - 2 + (s); \
      int rn = pn < 0 ? -pn : (pn > N_-1 ? 2*(N_-1)-pn : pn); \
      vnxt = b2f(ab[(long)rn*N_ + m]); \
    } \
    scratch[((s)&1)*1024 + m] = vcur; \
    __syncthreads(); \
    { \
      const float* rbp = &scratch[((s)&1)*1024]; \
      float rb = u0*rbp[nb0] + u1*rbp[nb1] + u2*rbp[nb2] + u3*rbp[nb3] \
               + u4*rbp[nb4] + u5*rbp[nb5] + u6*rbp[nb6]; \
      rbw0=rbw1; rbw1=rbw2; rbw2=rbw3; rbw3=rbw4; rbw4=rbw5; rbw5=rbw6; rbw6=rb; \
    } \
    vd0=vd1; vd1=vd2; vd2=vd3; vd3=vcur; \
    vcur = vnxt; \
    EMIT \
  }
#define BSP_EMIT(r) lg[r] = vd0 + au0*rbw0+au1*rbw1+au2*rbw2+au3*rbw3+au4*rbw4+au5*rbw5+au6*rbw6;

  BSP_STEP(0, )
  BSP_STEP(1, )
  BSP_STEP(2, )
  BSP_STEP(3, )
  BSP_STEP(4, )
  BSP_STEP(5, )
  BSP_STEP(6,  BSP_EMIT(0))
  BSP_STEP(7,  BSP_EMIT(1))
  BSP_STEP(8,  BSP_EMIT(2))
  BSP_STEP(9,  BSP_EMIT(3))
  BSP_STEP(10, BSP_EMIT(4))
  BSP_STEP(11, BSP_EMIT(5))
  BSP_STEP(12, BSP_EMIT(6))
  BSP_STEP(13, BSP_EMIT(7))
  BSP_STEP(14, BSP_EMIT(8))
  BSP_STEP(15, BSP_EMIT(9))
  BSP_STEP(16, BSP_EMIT(10))
  BSP_STEP(17, BSP_EMIT(11))
  BSP_STEP(18, BSP_EMIT(12))
  BSP_STEP(19, BSP_EMIT(13))
  BSP_STEP(20, BSP_EMIT(14))
  BSP_STEP(21, BSP_EMIT(15))
#undef BSP_STEP
#undef BSP_EMIT

  // ---- softmax over m (block-wide, batched for 16 rows) ----
#pragma unroll
  for (int r = 0; r < TM; ++r) {
    float mx = lg[r];
#pragma unroll
    for (int o = 32; o > 0; o >>= 1) mx = fmaxf(mx, __shfl_xor(mx, o, 64));
    if (lane == 0) scratch[2048 + wv*16 + r] = mx;
  }
  __syncthreads();
  if (tid < 16) {
    float mx = -1e30f;
#pragma unroll
    for (int ww = 0; ww < 16; ++ww) mx = fmaxf(mx, scratch[2048 + ww*16 + tid]);
    bmax[tid] = mx;
  }
  __syncthreads();
#pragma unroll
  for (int r = 0; r < TM; ++r) {
    float e = __expf(lg[r] - bmax[r]);
    P[r][m] = f2b(e);
    lg[r] = e;
  }
#pragma unroll
  for (int r = 0; r < TM; ++r) {
    float sm = lg[r];
#pragma unroll
    for (int o = 32; o > 0; o >>= 1) sm += __shfl_xor(sm, o, 64);
    if (lane == 0) scratch[2304 + wv*16 + r] = sm;
  }
  __syncthreads();
  if (tid < 16) {
    float sm = 0.f;
#pragma unroll
    for (int ww = 0; ww < 16; ++ww) sm += scratch[2304 + ww*16 + tid];
    bsum[tid] = sm;
  }
  __syncthreads();   // P + bsum ready; scratch free for PV partials

  // ---- PV via MFMA: out[16][64] = P[16][1024] @ V[1024][64] ----
  int dt = wv & 3, kc = wv >> 2;
  int qd = lane >> 4, l16 = lane & 15;
  f32x4 pvacc = {0.f, 0.f, 0.f, 0.f};
  const ushort_t* vtb = vt + ((long)bh*D_ + dt*16 + l16)*N_;
#pragma unroll
  for (int s = 0; s < 8; ++s) {
    int k0 = kc*256 + s*32 + qd*8;
    bf16x8 afrag = *(const bf16x8*)&P[l16][k0];
    bf16x8 bfrag = *(const bf16x8*)(vtb + k0);
    pvacc = __builtin_amdgcn_mfma_f32_16x16x32_bf16(afrag, bfrag, pvacc, 0, 0, 0);
  }
  if (kc > 0) {
    *(f32x4*)(scratch + ((kc-1)*4 + dt)*256 + lane*4) = pvacc;
  }
  __syncthreads();
  if (kc == 0) {
#pragma unroll
    for (int j = 0; j < 3; ++j) {
      f32x4 o = *(const f32x4*)(scratch + (j*4 + dt)*256 + lane*4);
      pvacc += o;
    }
#pragma unroll
    for (int r = 0; r < 4; ++r) {
      int row = qd*4 + r;
      ao[((long)bh*N_ + n0 + row)*D_ + dt*16 + l16] = pvacc[r] / bsum[row];
    }
  }
}

// ---------------- proj GEMM (8192x320 @ 320x320^T), gathered A ----------------
__global__ __launch_bounds__(256) void proj_kernel(const float* __restrict__ ao,
    const float* __restrict__ w, const float* __restrict__ bias,
    float* __restrict__ out) {
  __shared__ float As[16][68];
  __shared__ float Bs[16][68];
  int j0 = blockIdx.x * 64;
  int m0 = blockIdx.y * 64;
  int tid = threadIdx.x;
  int tx = tid & 15, ty = tid >> 4;
  int lr = tid >> 2;
  int lc = (tid & 3) << 2;
  int m = m0 + lr;
  int bb2 = m >> 10, n = m & (N_-1);
  float acc[4][4] = {};
  for (int kk = 0; kk < C_; kk += 16) {
    int kcol = kk + lc;
    int h = kcol >> 6, dd = kcol & 63;
    float4 a4 = *(const float4*)(ao + (((long)bb2*H_ + h)*N_ + n)*D_ + dd);
    float4 b4 = *(const float4*)(w + (long)(j0+lr)*C_ + kcol);
    As[lc+0][lr]=a4.x; As[lc+1][lr]=a4.y; As[lc+2][lr]=a4.z; As[lc+3][lr]=a4.w;
    Bs[lc+0][lr]=b4.x; Bs[lc+1][lr]=b4.y; Bs[lc+2][lr]=b4.z; Bs[lc+3][lr]=b4.w;
    __syncthreads();
#pragma unroll
    for (int p = 0; p < 16; ++p) {
      float4 av = *(const float4*)&As[p][ty<<2];
      float4 bv = *(const float4*)&Bs[p][tx<<2];
      float aa[4] = {av.x,av.y,av.z,av.w};
      float bb[4] = {bv.x,bv.y,bv.z,bv.w};
#pragma unroll
      for (int i=0;i<4;++i)
#pragma unroll
        for (int j=0;j<4;++j) acc[i][j] += aa[i]*bb[j];
    }
    __syncthreads();
  }
#pragma unroll
  for (int i=0;i<4;++i) {
    int mm = m0 + (ty<<2) + i;
    float* orow = out + (long)mm*C_ + j0 + (tx<<2);
    float4 bi = *(const float4*)(bias + j0 + (tx<<2));
    float4 st = make_float4(acc[i][0]+bi.x, acc[i][1]+bi.y,
                            acc[i][2]+bi.z, acc[i][3]+bi.w);
    *(float4*)orow = st;
  }
}

extern "C" void kernel_launch(void* const* d_in, const int* in_sizes, int n_in,
                              void* d_out, int out_size, void* d_ws, size_t ws_size,
                              hipStream_t stream) {
  const float* x      = (const float*)d_in[0];
  const float* ln_g   = (const float*)d_in[1];
  const float* ln_b   = (const float*)d_in[2];
  const float* qkv_w  = (const float*)d_in[3];
  const float* qkv_b  = (const float*)d_in[4];
  const float* proj_w = (const float*)d_in[5];
  const float* proj_b = (const float*)d_in[6];
  float* out = (float*)d_out;

  char* ws = (char*)d_ws;
  const long sz_bhnd = (long)B_*H_*N_*D_;   // 2,621,440
  float*    xn   = (float*)ws;                      ws += (long)M_*C_*4;
  float*    ao   = (float*)ws;                      ws += sz_bhnd*4;
  ushort_t* q    = (ushort_t*)ws;                   ws += sz_bhnd*2;
  ushort_t* k    = (ushort_t*)ws;                   ws += sz_bhnd*2;
  ushort_t* vt   = (ushort_t*)ws;                   ws += sz_bhnd*2;
  ushort_t* attn = (ushort_t*)ws;                   // 40*1024*1024*2 B = 84 MB

  // Host-side 1D Gaussian kernels (separable: K = outer(u,u))
  Gauss gw;
  const float sig[H_] = {1.f, 2.f, 3.f, 4.f, 5.f};
  for (int h = 0; h < H_; ++h) {
    float g[7], s = 0.f;
    for (int t = 0; t < 7; ++t) {
      float xx = (float)(t - 3);
      g[t] = expf(-xx*xx / (2.f*sig[h]*sig[h]));
      s += g[t];
    }
    float alpha = 0.1f * (float)(h+1);
    for (int t = 0; t < 7; ++t) {
      gw.u[h][t]  = g[t] / s;
      gw.au[h][t] = alpha * g[t] / s;
    }
  }

  ln_kernel<<<M_, 64, 0, stream>>>(x, ln_g, ln_b, xn);
  qkv_kernel<<<dim3(15, 128), 256, 0, stream>>>(xn, qkv_w, qkv_b, q, k, vt);
  qk_kernel<<<dim3(8, 8, B_*H_), 256, 0, stream>>>(q, k, attn);
  bsp_kernel<<<dim3(N_/TM, B_*H_), 1024, 0, stream>>>(attn, vt, ao, gw);
  proj_kernel<<<dim3(5, 128), 256, 0, stream>>>(ao, proj_w, proj_b, out);
}

// Round 4
// 523.530 us; speedup vs baseline: 1.3630x; 1.3630x over previous
//
#include <hip/hip_runtime.h>
#include <math.h>

#define B_ 8
#define N_ 1024
#define C_ 320
#define H_ 5
#define D_ 64
#define M_ (B_*N_)
#define TM 16

typedef unsigned short ushort_t;
typedef __attribute__((ext_vector_type(8))) short bf16x8;
typedef __attribute__((ext_vector_type(4))) float f32x4;

struct Gauss {
  float u[H_][7];   // 1D gaussian (normalized)
  float au[H_][7];  // alpha * u
};

// fp32 -> bf16 RNE (manual, version-stable)
__device__ __forceinline__ ushort_t f2b(float f) {
  union { float f; unsigned u; } c; c.f = f;
  unsigned r = c.u + 0x7fffu + ((c.u >> 16) & 1u);
  return (ushort_t)(r >> 16);
}
__device__ __forceinline__ float b2f(ushort_t u) {
  union { float f; unsigned u; } c; c.u = ((unsigned)u) << 16;
  return c.f;
}

// ---------------- LayerNorm: one wave per row ----------------
__global__ __launch_bounds__(64) void ln_kernel(const float* __restrict__ x,
    const float* __restrict__ gamma, const float* __restrict__ beta,
    float* __restrict__ xn) {
  int row = blockIdx.x;
  int lane = threadIdx.x;
  const float* xr = x + (long)row * C_;
  float vals[5];
  float s = 0.f, ss = 0.f;
#pragma unroll
  for (int j = 0; j < 5; ++j) {
    float vv = xr[lane + 64*j];
    vals[j] = vv; s += vv; ss += vv*vv;
  }
#pragma unroll
  for (int o = 32; o > 0; o >>= 1) {
    s  += __shfl_xor(s, o, 64);
    ss += __shfl_xor(ss, o, 64);
  }
  float mean = s * (1.0f/C_);
  float var  = ss * (1.0f/C_) - mean*mean;
  float rstd = rsqrtf(var + 1e-5f);
  float* outr = xn + (long)row * C_;
#pragma unroll
  for (int j = 0; j < 5; ++j) {
    int c = lane + 64*j;
    outr[c] = (vals[j]-mean)*rstd*gamma[c] + beta[c];
  }
}

// ---------------- QKV GEMM (8192x320 @ 320x960^T) + scatter ----------------
// q (pre-scaled by d^-0.5) and k stored bf16 in (B,H,N,d); v TRANSPOSED bf16 vt[bh][d][n]
__global__ __launch_bounds__(256) void qkv_kernel(const float* __restrict__ xn,
    const float* __restrict__ w, const float* __restrict__ bias,
    ushort_t* __restrict__ q, ushort_t* __restrict__ k, ushort_t* __restrict__ vt) {
  __shared__ float As[16][68];
  __shared__ float Bs[16][68];
  int j0 = blockIdx.x * 64;
  int m0 = blockIdx.y * 64;
  int tid = threadIdx.x;
  int tx = tid & 15, ty = tid >> 4;
  int lr = tid >> 2;
  int lc = (tid & 3) << 2;
  float acc[4][4] = {};
  for (int kk = 0; kk < C_; kk += 16) {
    float4 a4 = *(const float4*)(xn + (long)(m0+lr)*C_ + kk + lc);
    float4 b4 = *(const float4*)(w  + (long)(j0+lr)*C_ + kk + lc);
    As[lc+0][lr]=a4.x; As[lc+1][lr]=a4.y; As[lc+2][lr]=a4.z; As[lc+3][lr]=a4.w;
    Bs[lc+0][lr]=b4.x; Bs[lc+1][lr]=b4.y; Bs[lc+2][lr]=b4.z; Bs[lc+3][lr]=b4.w;
    __syncthreads();
#pragma unroll
    for (int p = 0; p < 16; ++p) {
      float4 av = *(const float4*)&As[p][ty<<2];
      float4 bv = *(const float4*)&Bs[p][tx<<2];
      float aa[4] = {av.x,av.y,av.z,av.w};
      float bb[4] = {bv.x,bv.y,bv.z,bv.w};
#pragma unroll
      for (int i=0;i<4;++i)
#pragma unroll
        for (int j=0;j<4;++j) acc[i][j] += aa[i]*bb[j];
    }
    __syncthreads();
  }
#pragma unroll
  for (int i=0;i<4;++i) {
    int m = m0 + (ty<<2) + i;
    int bb2 = m >> 10, n = m & (N_-1);
#pragma unroll
    for (int j=0;j<4;++j) {
      int col = j0 + (tx<<2) + j;
      float val = acc[i][j] + bias[col];
      int three = col / 320;
      int rem = col - three*320;
      int h = rem >> 6, dd = rem & 63;
      if (three == 0) {
        q[(((long)bb2*H_ + h)*N_ + n)*D_ + dd] = f2b(val * 0.125f);  // fold d^-0.5
      } else if (three == 1) {
        k[(((long)bb2*H_ + h)*N_ + n)*D_ + dd] = f2b(val);
      } else {
        vt[(((long)bb2*H_ + h)*D_ + dd)*N_ + n] = f2b(val);
      }
    }
  }
}

// ---------------- QK^T per (b,h) via MFMA bf16: 128x128 tile / block ----------------
__global__ __launch_bounds__(256, 4) void qk_kernel(const ushort_t* __restrict__ q,
    const ushort_t* __restrict__ kmat, ushort_t* __restrict__ attn) {
  __shared__ __align__(16) ushort_t Qs[128][72];  // +8 pad: 2-way bank alias (free)
  __shared__ __align__(16) ushort_t Ks[128][72];
  int bh = blockIdx.z;
  int m0 = blockIdx.x * 128;   // query rows
  int n0 = blockIdx.y * 128;   // key cols
  int tid = threadIdx.x;
  int lane = tid & 63, wv = tid >> 6;
  int l16 = lane & 15, qd = lane >> 4;
  const ushort_t* qb = q    + ((long)bh*N_ + m0)*D_;
  const ushort_t* kb = kmat + ((long)bh*N_ + n0)*D_;
#pragma unroll
  for (int i = 0; i < 4; ++i) {
    int chunk = tid + 256*i;            // 1024 chunks of 8 bf16
    int row = chunk >> 3, c8 = (chunk & 7) << 3;
    *(uint4*)&Qs[row][c8] = *(const uint4*)(qb + (long)row*D_ + c8);
    *(uint4*)&Ks[row][c8] = *(const uint4*)(kb + (long)row*D_ + c8);
  }
  __syncthreads();
  f32x4 acc[2][8];
#pragma unroll
  for (int i=0;i<2;++i)
#pragma unroll
    for (int j=0;j<8;++j) acc[i][j] = (f32x4){0.f,0.f,0.f,0.f};
#pragma unroll
  for (int ks = 0; ks < 2; ++ks) {
    int k0 = ks*32 + qd*8;
    bf16x8 a0 = *(const bf16x8*)&Qs[wv*32 + l16][k0];
    bf16x8 a1 = *(const bf16x8*)&Qs[wv*32 + 16 + l16][k0];
#pragma unroll
    for (int ct = 0; ct < 8; ++ct) {
      bf16x8 b = *(const bf16x8*)&Ks[ct*16 + l16][k0];
      acc[0][ct] = __builtin_amdgcn_mfma_f32_16x16x32_bf16(a0, b, acc[0][ct], 0,0,0);
      acc[1][ct] = __builtin_amdgcn_mfma_f32_16x16x32_bf16(a1, b, acc[1][ct], 0,0,0);
    }
  }
  ushort_t* ob = attn + ((long)bh*N_ + m0 + wv*32)*N_ + n0;
#pragma unroll
  for (int rt = 0; rt < 2; ++rt)
#pragma unroll
    for (int r = 0; r < 4; ++r) {
      long rowoff = (long)(rt*16 + qd*4 + r)*N_;
#pragma unroll
      for (int ct = 0; ct < 8; ++ct)
        ob[rowoff + ct*16 + l16] = f2b(acc[rt][ct][r]);
    }
}

// ------- Fused separable blur + softmax + MFMA PV (spill-proof delay-line) -------
// NOTE: no min-waves launch bound — a (1024,8) bound forced VGPR cap 32 and
// 1.1 GB/dispatch of scratch spill (measured R2/R3). 1 block/CU at ~100 VGPR
// is the fast configuration.
__global__ __launch_bounds__(1024) void bsp_kernel(
    const ushort_t* __restrict__ attn, const ushort_t* __restrict__ vt,
    float* __restrict__ ao, Gauss gw) {
  __shared__ ushort_t P[TM][1032];    // bf16 exp(logits); +8 pad for A-frag banking
  __shared__ float scratch[4096];     // [0..2047] dbuf rowbuf | [2048..2559] reductions | PV partials
  __shared__ float bmax[TM], bsum[TM];

  int bh = blockIdx.y;
  int h = bh % H_;
  int n0 = blockIdx.x * TM;
  int tid = threadIdx.x;
  int m = tid;
  int lane = tid & 63, wv = tid >> 6;
  const ushort_t* ab = attn + (long)bh*N_*N_;

  // block-uniform coefficients -> SGPRs
  float u0 = gw.u[h][0], u1 = gw.u[h][1], u2 = gw.u[h][2], u3 = gw.u[h][3],
        u4 = gw.u[h][4], u5 = gw.u[h][5], u6 = gw.u[h][6];
  float au0 = gw.au[h][0], au1 = gw.au[h][1], au2 = gw.au[h][2], au3 = gw.au[h][3],
        au4 = gw.au[h][4], au5 = gw.au[h][5], au6 = gw.au[h][6];

  // column-neighbor indices with reflect (named scalars: no dynamic indexing)
  int nb0 = m >= 3 ? m-3 : 3-m;
  int nb1 = m >= 2 ? m-2 : 2-m;
  int nb2 = m >= 1 ? m-1 : 1-m;
  int nb3 = m;
  int nb4 = m+1 <= N_-1 ? m+1 : 2*(N_-1)-(m+1);
  int nb5 = m+2 <= N_-1 ? m+2 : 2*(N_-1)-(m+2);
  int nb6 = m+3 <= N_-1 ? m+3 : 2*(N_-1)-(m+3);

  float rbw0=0,rbw1=0,rbw2=0,rbw3=0,rbw4=0,rbw5=0,rbw6=0;  // rb delay line
  float vd0=0,vd1=0,vd2=0,vd3=0;                            // raw-val delay line
  float lg[16];
  float vcur, vnxt = 0.f;
  {
    int p = n0 - 3;
    int rr = p < 0 ? -p : p;
    vcur = b2f(ab[(long)rr*N_ + m]);
  }

#define BSP_STEP(s, EMIT) \
  { \
    if ((s) < 21) { \
      int pn = n0 - 2 + (s); \
      int rn = pn < 0 ? -pn : (pn > N_-1 ? 2*(N_-1)-pn : pn); \
      vnxt = b2f(ab[(long)rn*N_ + m]); \
    } \
    scratch[((s)&1)*1024 + m] = vcur; \
    __syncthreads(); \
    { \
      const float* rbp = &scratch[((s)&1)*1024]; \
      float rb = u0*rbp[nb0] + u1*rbp[nb1] + u2*rbp[nb2] + u3*rbp[nb3] \
               + u4*rbp[nb4] + u5*rbp[nb5] + u6*rbp[nb6]; \
      rbw0=rbw1; rbw1=rbw2; rbw2=rbw3; rbw3=rbw4; rbw4=rbw5; rbw5=rbw6; rbw6=rb; \
    } \
    vd0=vd1; vd1=vd2; vd2=vd3; vd3=vcur; \
    vcur = vnxt; \
    EMIT \
  }
#define BSP_EMIT(r) lg[r] = vd0 + au0*rbw0+au1*rbw1+au2*rbw2+au3*rbw3+au4*rbw4+au5*rbw5+au6*rbw6;

  BSP_STEP(0, )
  BSP_STEP(1, )
  BSP_STEP(2, )
  BSP_STEP(3, )
  BSP_STEP(4, )
  BSP_STEP(5, )
  BSP_STEP(6,  BSP_EMIT(0))
  BSP_STEP(7,  BSP_EMIT(1))
  BSP_STEP(8,  BSP_EMIT(2))
  BSP_STEP(9,  BSP_EMIT(3))
  BSP_STEP(10, BSP_EMIT(4))
  BSP_STEP(11, BSP_EMIT(5))
  BSP_STEP(12, BSP_EMIT(6))
  BSP_STEP(13, BSP_EMIT(7))
  BSP_STEP(14, BSP_EMIT(8))
  BSP_STEP(15, BSP_EMIT(9))
  BSP_STEP(16, BSP_EMIT(10))
  BSP_STEP(17, BSP_EMIT(11))
  BSP_STEP(18, BSP_EMIT(12))
  BSP_STEP(19, BSP_EMIT(13))
  BSP_STEP(20, BSP_EMIT(14))
  BSP_STEP(21, BSP_EMIT(15))
#undef BSP_STEP
#undef BSP_EMIT

  // ---- softmax over m (block-wide, batched for 16 rows) ----
#pragma unroll
  for (int r = 0; r < TM; ++r) {
    float mx = lg[r];
#pragma unroll
    for (int o = 32; o > 0; o >>= 1) mx = fmaxf(mx, __shfl_xor(mx, o, 64));
    if (lane == 0) scratch[2048 + wv*16 + r] = mx;
  }
  __syncthreads();
  if (tid < 16) {
    float mx = -1e30f;
#pragma unroll
    for (int ww = 0; ww < 16; ++ww) mx = fmaxf(mx, scratch[2048 + ww*16 + tid]);
    bmax[tid] = mx;
  }
  __syncthreads();
#pragma unroll
  for (int r = 0; r < TM; ++r) {
    float e = __expf(lg[r] - bmax[r]);
    P[r][m] = f2b(e);
    lg[r] = e;
  }
#pragma unroll
  for (int r = 0; r < TM; ++r) {
    float sm = lg[r];
#pragma unroll
    for (int o = 32; o > 0; o >>= 1) sm += __shfl_xor(sm, o, 64);
    if (lane == 0) scratch[2304 + wv*16 + r] = sm;
  }
  __syncthreads();
  if (tid < 16) {
    float sm = 0.f;
#pragma unroll
    for (int ww = 0; ww < 16; ++ww) sm += scratch[2304 + ww*16 + tid];
    bsum[tid] = sm;
  }
  __syncthreads();   // P + bsum ready; scratch free for PV partials

  // ---- PV via MFMA: out[16][64] = P[16][1024] @ V[1024][64] ----
  int dt = wv & 3, kc = wv >> 2;
  int qd = lane >> 4, l16 = lane & 15;
  f32x4 pvacc = {0.f, 0.f, 0.f, 0.f};
  const ushort_t* vtb = vt + ((long)bh*D_ + dt*16 + l16)*N_;
#pragma unroll
  for (int s = 0; s < 8; ++s) {
    int k0 = kc*256 + s*32 + qd*8;
    bf16x8 afrag = *(const bf16x8*)&P[l16][k0];
    bf16x8 bfrag = *(const bf16x8*)(vtb + k0);
    pvacc = __builtin_amdgcn_mfma_f32_16x16x32_bf16(afrag, bfrag, pvacc, 0, 0, 0);
  }
  if (kc > 0) {
    *(f32x4*)(scratch + ((kc-1)*4 + dt)*256 + lane*4) = pvacc;
  }
  __syncthreads();
  if (kc == 0) {
#pragma unroll
    for (int j = 0; j < 3; ++j) {
      f32x4 o = *(const f32x4*)(scratch + (j*4 + dt)*256 + lane*4);
      pvacc += o;
    }
#pragma unroll
    for (int r = 0; r < 4; ++r) {
      int row = qd*4 + r;
      ao[((long)bh*N_ + n0 + row)*D_ + dt*16 + l16] = pvacc[r] / bsum[row];
    }
  }
}

// ---------------- proj GEMM (8192x320 @ 320x320^T), gathered A ----------------
__global__ __launch_bounds__(256) void proj_kernel(const float* __restrict__ ao,
    const float* __restrict__ w, const float* __restrict__ bias,
    float* __restrict__ out) {
  __shared__ float As[16][68];
  __shared__ float Bs[16][68];
  int j0 = blockIdx.x * 64;
  int m0 = blockIdx.y * 64;
  int tid = threadIdx.x;
  int tx = tid & 15, ty = tid >> 4;
  int lr = tid >> 2;
  int lc = (tid & 3) << 2;
  int m = m0 + lr;
  int bb2 = m >> 10, n = m & (N_-1);
  float acc[4][4] = {};
  for (int kk = 0; kk < C_; kk += 16) {
    int kcol = kk + lc;
    int h = kcol >> 6, dd = kcol & 63;
    float4 a4 = *(const float4*)(ao + (((long)bb2*H_ + h)*N_ + n)*D_ + dd);
    float4 b4 = *(const float4*)(w + (long)(j0+lr)*C_ + kcol);
    As[lc+0][lr]=a4.x; As[lc+1][lr]=a4.y; As[lc+2][lr]=a4.z; As[lc+3][lr]=a4.w;
    Bs[lc+0][lr]=b4.x; Bs[lc+1][lr]=b4.y; Bs[lc+2][lr]=b4.z; Bs[lc+3][lr]=b4.w;
    __syncthreads();
#pragma unroll
    for (int p = 0; p < 16; ++p) {
      float4 av = *(const float4*)&As[p][ty<<2];
      float4 bv = *(const float4*)&Bs[p][tx<<2];
      float aa[4] = {av.x,av.y,av.z,av.w};
      float bb[4] = {bv.x,bv.y,bv.z,bv.w};
#pragma unroll
      for (int i=0;i<4;++i)
#pragma unroll
        for (int j=0;j<4;++j) acc[i][j] += aa[i]*bb[j];
    }
    __syncthreads();
  }
#pragma unroll
  for (int i=0;i<4;++i) {
    int mm = m0 + (ty<<2) + i;
    float* orow = out + (long)mm*C_ + j0 + (tx<<2);
    float4 bi = *(const float4*)(bias + j0 + (tx<<2));
    float4 st = make_float4(acc[i][0]+bi.x, acc[i][1]+bi.y,
                            acc[i][2]+bi.z, acc[i][3]+bi.w);
    *(float4*)orow = st;
  }
}

extern "C" void kernel_launch(void* const* d_in, const int* in_sizes, int n_in,
                              void* d_out, int out_size, void* d_ws, size_t ws_size,
                              hipStream_t stream) {
  const float* x      = (const float*)d_in[0];
  const float* ln_g   = (const float*)d_in[1];
  const float* ln_b   = (const float*)d_in[2];
  const float* qkv_w  = (const float*)d_in[3];
  const float* qkv_b  = (const float*)d_in[4];
  const float* proj_w = (const float*)d_in[5];
  const float* proj_b = (const float*)d_in[6];
  float* out = (float*)d_out;

  char* ws = (char*)d_ws;
  const long sz_bhnd = (long)B_*H_*N_*D_;   // 2,621,440
  float*    xn   = (float*)ws;                      ws += (long)M_*C_*4;
  float*    ao   = (float*)ws;                      ws += sz_bhnd*4;
  ushort_t* q    = (ushort_t*)ws;                   ws += sz_bhnd*2;
  ushort_t* k    = (ushort_t*)ws;                   ws += sz_bhnd*2;
  ushort_t* vt   = (ushort_t*)ws;                   ws += sz_bhnd*2;
  ushort_t* attn = (ushort_t*)ws;                   // 40*1024*1024*2 B = 84 MB

  // Host-side 1D Gaussian kernels (separable: K = outer(u,u))
  Gauss gw;
  const float sig[H_] = {1.f, 2.f, 3.f, 4.f, 5.f};
  for (int h = 0; h < H_; ++h) {
    float g[7], s = 0.f;
    for (int t = 0; t < 7; ++t) {
      float xx = (float)(t - 3);
      g[t] = expf(-xx*xx / (2.f*sig[h]*sig[h]));
      s += g[t];
    }
    float alpha = 0.1f * (float)(h+1);
    for (int t = 0; t < 7; ++t) {
      gw.u[h][t]  = g[t] / s;
      gw.au[h][t] = alpha * g[t] / s;
    }
  }

  ln_kernel<<<M_, 64, 0, stream>>>(x, ln_g, ln_b, xn);
  qkv_kernel<<<dim3(15, 128), 256, 0, stream>>>(xn, qkv_w, qkv_b, q, k, vt);
  qk_kernel<<<dim3(8, 8, B_*H_), 256, 0, stream>>>(q, k, attn);
  bsp_kernel<<<dim3(N_/TM, B_*H_), 1024, 0, stream>>>(attn, vt, ao, gw);
  proj_kernel<<<dim3(5, 128), 256, 0, stream>>>(ao, proj_w, proj_b, out);
}

// Round 5
// 520.354 us; speedup vs baseline: 1.3713x; 1.0061x over previous
//
#include <hip/hip_runtime.h>
#include <math.h>

#define B_ 8
#define N_ 1024
#define C_ 320
#define H_ 5
#define D_ 64
#define M_ (B_*N_)
#define TM 16

typedef unsigned short ushort_t;
typedef __attribute__((ext_vector_type(8))) short bf16x8;
typedef __attribute__((ext_vector_type(4))) float f32x4;

struct Gauss {
  float u[H_][7];   // 1D gaussian (normalized)
  float au[H_][7];  // alpha * u
};

// fp32 -> bf16 RNE (manual, version-stable)
__device__ __forceinline__ ushort_t f2b(float f) {
  union { float f; unsigned u; } c; c.f = f;
  unsigned r = c.u + 0x7fffu + ((c.u >> 16) & 1u);
  return (ushort_t)(r >> 16);
}
__device__ __forceinline__ float b2f(ushort_t u) {
  union { float f; unsigned u; } c; c.u = ((unsigned)u) << 16;
  return c.f;
}

// ---------------- LayerNorm: one wave per row ----------------
__global__ __launch_bounds__(64) void ln_kernel(const float* __restrict__ x,
    const float* __restrict__ gamma, const float* __restrict__ beta,
    float* __restrict__ xn) {
  int row = blockIdx.x;
  int lane = threadIdx.x;
  const float* xr = x + (long)row * C_;
  float vals[5];
  float s = 0.f, ss = 0.f;
#pragma unroll
  for (int j = 0; j < 5; ++j) {
    float vv = xr[lane + 64*j];
    vals[j] = vv; s += vv; ss += vv*vv;
  }
#pragma unroll
  for (int o = 32; o > 0; o >>= 1) {
    s  += __shfl_xor(s, o, 64);
    ss += __shfl_xor(ss, o, 64);
  }
  float mean = s * (1.0f/C_);
  float var  = ss * (1.0f/C_) - mean*mean;
  float rstd = rsqrtf(var + 1e-5f);
  float* outr = xn + (long)row * C_;
#pragma unroll
  for (int j = 0; j < 5; ++j) {
    int c = lane + 64*j;
    outr[c] = (vals[j]-mean)*rstd*gamma[c] + beta[c];
  }
}

// ---------------- QKV GEMM (8192x320 @ 320x960^T) + scatter ----------------
// q (pre-scaled by d^-0.5) and k stored bf16 in (B,H,N,d); v TRANSPOSED bf16 vt[bh][d][n]
__global__ __launch_bounds__(256) void qkv_kernel(const float* __restrict__ xn,
    const float* __restrict__ w, const float* __restrict__ bias,
    ushort_t* __restrict__ q, ushort_t* __restrict__ k, ushort_t* __restrict__ vt) {
  __shared__ float As[16][68];
  __shared__ float Bs[16][68];
  int j0 = blockIdx.x * 64;
  int m0 = blockIdx.y * 64;
  int tid = threadIdx.x;
  int tx = tid & 15, ty = tid >> 4;
  int lr = tid >> 2;
  int lc = (tid & 3) << 2;
  float acc[4][4] = {};
  for (int kk = 0; kk < C_; kk += 16) {
    float4 a4 = *(const float4*)(xn + (long)(m0+lr)*C_ + kk + lc);
    float4 b4 = *(const float4*)(w  + (long)(j0+lr)*C_ + kk + lc);
    As[lc+0][lr]=a4.x; As[lc+1][lr]=a4.y; As[lc+2][lr]=a4.z; As[lc+3][lr]=a4.w;
    Bs[lc+0][lr]=b4.x; Bs[lc+1][lr]=b4.y; Bs[lc+2][lr]=b4.z; Bs[lc+3][lr]=b4.w;
    __syncthreads();
#pragma unroll
    for (int p = 0; p < 16; ++p) {
      float4 av = *(const float4*)&As[p][ty<<2];
      float4 bv = *(const float4*)&Bs[p][tx<<2];
      float aa[4] = {av.x,av.y,av.z,av.w};
      float bb[4] = {bv.x,bv.y,bv.z,bv.w};
#pragma unroll
      for (int i=0;i<4;++i)
#pragma unroll
        for (int j=0;j<4;++j) acc[i][j] += aa[i]*bb[j];
    }
    __syncthreads();
  }
#pragma unroll
  for (int i=0;i<4;++i) {
    int m = m0 + (ty<<2) + i;
    int bb2 = m >> 10, n = m & (N_-1);
#pragma unroll
    for (int j=0;j<4;++j) {
      int col = j0 + (tx<<2) + j;
      float val = acc[i][j] + bias[col];
      int three = col / 320;
      int rem = col - three*320;
      int h = rem >> 6, dd = rem & 63;
      if (three == 0) {
        q[(((long)bb2*H_ + h)*N_ + n)*D_ + dd] = f2b(val * 0.125f);  // fold d^-0.5
      } else if (three == 1) {
        k[(((long)bb2*H_ + h)*N_ + n)*D_ + dd] = f2b(val);
      } else {
        vt[(((long)bb2*H_ + h)*D_ + dd)*N_ + n] = f2b(val);
      }
    }
  }
}

// ---------------- QK^T per (b,h) via MFMA bf16: 128x128 tile / block ----------------
__global__ __launch_bounds__(256, 4) void qk_kernel(const ushort_t* __restrict__ q,
    const ushort_t* __restrict__ kmat, ushort_t* __restrict__ attn) {
  __shared__ __align__(16) ushort_t Qs[128][72];  // +8 pad: 2-way bank alias (free)
  __shared__ __align__(16) ushort_t Ks[128][72];
  int bh = blockIdx.z;
  int m0 = blockIdx.x * 128;   // query rows
  int n0 = blockIdx.y * 128;   // key cols
  int tid = threadIdx.x;
  int lane = tid & 63, wv = tid >> 6;
  int l16 = lane & 15, qd = lane >> 4;
  const ushort_t* qb = q    + ((long)bh*N_ + m0)*D_;
  const ushort_t* kb = kmat + ((long)bh*N_ + n0)*D_;
#pragma unroll
  for (int i = 0; i < 4; ++i) {
    int chunk = tid + 256*i;            // 1024 chunks of 8 bf16
    int row = chunk >> 3, c8 = (chunk & 7) << 3;
    *(uint4*)&Qs[row][c8] = *(const uint4*)(qb + (long)row*D_ + c8);
    *(uint4*)&Ks[row][c8] = *(const uint4*)(kb + (long)row*D_ + c8);
  }
  __syncthreads();
  f32x4 acc[2][8];
#pragma unroll
  for (int i=0;i<2;++i)
#pragma unroll
    for (int j=0;j<8;++j) acc[i][j] = (f32x4){0.f,0.f,0.f,0.f};
#pragma unroll
  for (int ks = 0; ks < 2; ++ks) {
    int k0 = ks*32 + qd*8;
    bf16x8 a0 = *(const bf16x8*)&Qs[wv*32 + l16][k0];
    bf16x8 a1 = *(const bf16x8*)&Qs[wv*32 + 16 + l16][k0];
#pragma unroll
    for (int ct = 0; ct < 8; ++ct) {
      bf16x8 b = *(const bf16x8*)&Ks[ct*16 + l16][k0];
      acc[0][ct] = __builtin_amdgcn_mfma_f32_16x16x32_bf16(a0, b, acc[0][ct], 0,0,0);
      acc[1][ct] = __builtin_amdgcn_mfma_f32_16x16x32_bf16(a1, b, acc[1][ct], 0,0,0);
    }
  }
  ushort_t* ob = attn + ((long)bh*N_ + m0 + wv*32)*N_ + n0;
#pragma unroll
  for (int rt = 0; rt < 2; ++rt)
#pragma unroll
    for (int r = 0; r < 4; ++r) {
      long rowoff = (long)(rt*16 + qd*4 + r)*N_;
#pragma unroll
      for (int ct = 0; ct < 8; ++ct)
        ob[rowoff + ct*16 + l16] = f2b(acc[rt][ct][r]);
    }
}

// ------- Fused separable blur + softmax + MFMA PV (spill-proof delay-line) -------
// VGPR history: (1024,8) bound -> cap 32, 1.1 GB spill; no bound -> compiler
// heuristic picked 64, 400 MB spill. (1024,4) = the HW structural limit for a
// 1024-thread block -> cap 128, fits the ~55 live VGPRs with margin.
__global__ __launch_bounds__(1024, 4) void bsp_kernel(
    const ushort_t* __restrict__ attn, const ushort_t* __restrict__ vt,
    float* __restrict__ ao, Gauss gw) {
  __shared__ ushort_t P[TM][1032];    // bf16 exp(logits); +8 pad for A-frag banking
  __shared__ float scratch[4096];     // [0..2047] dbuf rowbuf | [2048..2559] reductions | PV partials
  __shared__ float bmax[TM], bsum[TM];

  int bh = blockIdx.y;
  int h = bh % H_;
  int n0 = blockIdx.x * TM;
  int tid = threadIdx.x;
  int m = tid;
  int lane = tid & 63, wv = tid >> 6;
  const ushort_t* ab = attn + (long)bh*N_*N_;

  // block-uniform coefficients -> SGPRs
  float u0 = gw.u[h][0], u1 = gw.u[h][1], u2 = gw.u[h][2], u3 = gw.u[h][3],
        u4 = gw.u[h][4], u5 = gw.u[h][5], u6 = gw.u[h][6];
  float au0 = gw.au[h][0], au1 = gw.au[h][1], au2 = gw.au[h][2], au3 = gw.au[h][3],
        au4 = gw.au[h][4], au5 = gw.au[h][5], au6 = gw.au[h][6];

  // column-neighbor indices with reflect (named scalars: no dynamic indexing)
  int nb0 = m >= 3 ? m-3 : 3-m;
  int nb1 = m >= 2 ? m-2 : 2-m;
  int nb2 = m >= 1 ? m-1 : 1-m;
  int nb3 = m;
  int nb4 = m+1 <= N_-1 ? m+1 : 2*(N_-1)-(m+1);
  int nb5 = m+2 <= N_-1 ? m+2 : 2*(N_-1)-(m+2);
  int nb6 = m+3 <= N_-1 ? m+3 : 2*(N_-1)-(m+3);

  float rbw0=0,rbw1=0,rbw2=0,rbw3=0,rbw4=0,rbw5=0,rbw6=0;  // rb delay line
  float vd0=0,vd1=0,vd2=0,vd3=0;                            // raw-val delay line
  float lg[16];
  float vcur, vnxt = 0.f;
  {
    int p = n0 - 3;
    int rr = p < 0 ? -p : p;
    vcur = b2f(ab[(long)rr*N_ + m]);
  }

#define BSP_STEP(s, EMIT) \
  { \
    if ((s) < 21) { \
      int pn = n0 - 2 + (s); \
      int rn = pn < 0 ? -pn : (pn > N_-1 ? 2*(N_-1)-pn : pn); \
      vnxt = b2f(ab[(long)rn*N_ + m]); \
    } \
    scratch[((s)&1)*1024 + m] = vcur; \
    __syncthreads(); \
    { \
      const float* rbp = &scratch[((s)&1)*1024]; \
      float rb = u0*rbp[nb0] + u1*rbp[nb1] + u2*rbp[nb2] + u3*rbp[nb3] \
               + u4*rbp[nb4] + u5*rbp[nb5] + u6*rbp[nb6]; \
      rbw0=rbw1; rbw1=rbw2; rbw2=rbw3; rbw3=rbw4; rbw4=rbw5; rbw5=rbw6; rbw6=rb; \
    } \
    vd0=vd1; vd1=vd2; vd2=vd3; vd3=vcur; \
    vcur = vnxt; \
    EMIT \
  }
#define BSP_EMIT(r) lg[r] = vd0 + au0*rbw0+au1*rbw1+au2*rbw2+au3*rbw3+au4*rbw4+au5*rbw5+au6*rbw6;

  BSP_STEP(0, )
  BSP_STEP(1, )
  BSP_STEP(2, )
  BSP_STEP(3, )
  BSP_STEP(4, )
  BSP_STEP(5, )
  BSP_STEP(6,  BSP_EMIT(0))
  BSP_STEP(7,  BSP_EMIT(1))
  BSP_STEP(8,  BSP_EMIT(2))
  BSP_STEP(9,  BSP_EMIT(3))
  BSP_STEP(10, BSP_EMIT(4))
  BSP_STEP(11, BSP_EMIT(5))
  BSP_STEP(12, BSP_EMIT(6))
  BSP_STEP(13, BSP_EMIT(7))
  BSP_STEP(14, BSP_EMIT(8))
  BSP_STEP(15, BSP_EMIT(9))
  BSP_STEP(16, BSP_EMIT(10))
  BSP_STEP(17, BSP_EMIT(11))
  BSP_STEP(18, BSP_EMIT(12))
  BSP_STEP(19, BSP_EMIT(13))
  BSP_STEP(20, BSP_EMIT(14))
  BSP_STEP(21, BSP_EMIT(15))
#undef BSP_STEP
#undef BSP_EMIT

  // ---- softmax over m (block-wide, batched for 16 rows) ----
#pragma unroll
  for (int r = 0; r < TM; ++r) {
    float mx = lg[r];
#pragma unroll
    for (int o = 32; o > 0; o >>= 1) mx = fmaxf(mx, __shfl_xor(mx, o, 64));
    if (lane == 0) scratch[2048 + wv*16 + r] = mx;
  }
  __syncthreads();
  if (tid < 16) {
    float mx = -1e30f;
#pragma unroll
    for (int ww = 0; ww < 16; ++ww) mx = fmaxf(mx, scratch[2048 + ww*16 + tid]);
    bmax[tid] = mx;
  }
  __syncthreads();
#pragma unroll
  for (int r = 0; r < TM; ++r) {
    float e = __expf(lg[r] - bmax[r]);
    P[r][m] = f2b(e);
    lg[r] = e;
  }
#pragma unroll
  for (int r = 0; r < TM; ++r) {
    float sm = lg[r];
#pragma unroll
    for (int o = 32; o > 0; o >>= 1) sm += __shfl_xor(sm, o, 64);
    if (lane == 0) scratch[2304 + wv*16 + r] = sm;
  }
  __syncthreads();
  if (tid < 16) {
    float sm = 0.f;
#pragma unroll
    for (int ww = 0; ww < 16; ++ww) sm += scratch[2304 + ww*16 + tid];
    bsum[tid] = sm;
  }
  __syncthreads();   // P + bsum ready; scratch free for PV partials

  // ---- PV via MFMA: out[16][64] = P[16][1024] @ V[1024][64] ----
  int dt = wv & 3, kc = wv >> 2;
  int qd = lane >> 4, l16 = lane & 15;
  f32x4 pvacc = {0.f, 0.f, 0.f, 0.f};
  const ushort_t* vtb = vt + ((long)bh*D_ + dt*16 + l16)*N_;
#pragma unroll
  for (int s = 0; s < 8; ++s) {
    int k0 = kc*256 + s*32 + qd*8;
    bf16x8 afrag = *(const bf16x8*)&P[l16][k0];
    bf16x8 bfrag = *(const bf16x8*)(vtb + k0);
    pvacc = __builtin_amdgcn_mfma_f32_16x16x32_bf16(afrag, bfrag, pvacc, 0, 0, 0);
  }
  if (kc > 0) {
    *(f32x4*)(scratch + ((kc-1)*4 + dt)*256 + lane*4) = pvacc;
  }
  __syncthreads();
  if (kc == 0) {
#pragma unroll
    for (int j = 0; j < 3; ++j) {
      f32x4 o = *(const f32x4*)(scratch + (j*4 + dt)*256 + lane*4);
      pvacc += o;
    }
#pragma unroll
    for (int r = 0; r < 4; ++r) {
      int row = qd*4 + r;
      ao[((long)bh*N_ + n0 + row)*D_ + dt*16 + l16] = pvacc[r] / bsum[row];
    }
  }
}

// ---------------- proj GEMM (8192x320 @ 320x320^T), gathered A ----------------
__global__ __launch_bounds__(256) void proj_kernel(const float* __restrict__ ao,
    const float* __restrict__ w, const float* __restrict__ bias,
    float* __restrict__ out) {
  __shared__ float As[16][68];
  __shared__ float Bs[16][68];
  int j0 = blockIdx.x * 64;
  int m0 = blockIdx.y * 64;
  int tid = threadIdx.x;
  int tx = tid & 15, ty = tid >> 4;
  int lr = tid >> 2;
  int lc = (tid & 3) << 2;
  int m = m0 + lr;
  int bb2 = m >> 10, n = m & (N_-1);
  float acc[4][4] = {};
  for (int kk = 0; kk < C_; kk += 16) {
    int kcol = kk + lc;
    int h = kcol >> 6, dd = kcol & 63;
    float4 a4 = *(const float4*)(ao + (((long)bb2*H_ + h)*N_ + n)*D_ + dd);
    float4 b4 = *(const float4*)(w + (long)(j0+lr)*C_ + kcol);
    As[lc+0][lr]=a4.x; As[lc+1][lr]=a4.y; As[lc+2][lr]=a4.z; As[lc+3][lr]=a4.w;
    Bs[lc+0][lr]=b4.x; Bs[lc+1][lr]=b4.y; Bs[lc+2][lr]=b4.z; Bs[lc+3][lr]=b4.w;
    __syncthreads();
#pragma unroll
    for (int p = 0; p < 16; ++p) {
      float4 av = *(const float4*)&As[p][ty<<2];
      float4 bv = *(const float4*)&Bs[p][tx<<2];
      float aa[4] = {av.x,av.y,av.z,av.w};
      float bb[4] = {bv.x,bv.y,bv.z,bv.w};
#pragma unroll
      for (int i=0;i<4;++i)
#pragma unroll
        for (int j=0;j<4;++j) acc[i][j] += aa[i]*bb[j];
    }
    __syncthreads();
  }
#pragma unroll
  for (int i=0;i<4;++i) {
    int mm = m0 + (ty<<2) + i;
    float* orow = out + (long)mm*C_ + j0 + (tx<<2);
    float4 bi = *(const float4*)(bias + j0 + (tx<<2));
    float4 st = make_float4(acc[i][0]+bi.x, acc[i][1]+bi.y,
                            acc[i][2]+bi.z, acc[i][3]+bi.w);
    *(float4*)orow = st;
  }
}

extern "C" void kernel_launch(void* const* d_in, const int* in_sizes, int n_in,
                              void* d_out, int out_size, void* d_ws, size_t ws_size,
                              hipStream_t stream) {
  const float* x      = (const float*)d_in[0];
  const float* ln_g   = (const float*)d_in[1];
  const float* ln_b   = (const float*)d_in[2];
  const float* qkv_w  = (const float*)d_in[3];
  const float* qkv_b  = (const float*)d_in[4];
  const float* proj_w = (const float*)d_in[5];
  const float* proj_b = (const float*)d_in[6];
  float* out = (float*)d_out;

  char* ws = (char*)d_ws;
  const long sz_bhnd = (long)B_*H_*N_*D_;   // 2,621,440
  float*    xn   = (float*)ws;                      ws += (long)M_*C_*4;
  float*    ao   = (float*)ws;                      ws += sz_bhnd*4;
  ushort_t* q    = (ushort_t*)ws;                   ws += sz_bhnd*2;
  ushort_t* k    = (ushort_t*)ws;                   ws += sz_bhnd*2;
  ushort_t* vt   = (ushort_t*)ws;                   ws += sz_bhnd*2;
  ushort_t* attn = (ushort_t*)ws;                   // 40*1024*1024*2 B = 84 MB

  // Host-side 1D Gaussian kernels (separable: K = outer(u,u))
  Gauss gw;
  const float sig[H_] = {1.f, 2.f, 3.f, 4.f, 5.f};
  for (int h = 0; h < H_; ++h) {
    float g[7], s = 0.f;
    for (int t = 0; t < 7; ++t) {
      float xx = (float)(t - 3);
      g[t] = expf(-xx*xx / (2.f*sig[h]*sig[h]));
      s += g[t];
    }
    float alpha = 0.1f * (float)(h+1);
    for (int t = 0; t < 7; ++t) {
      gw.u[h][t]  = g[t] / s;
      gw.au[h][t] = alpha * g[t] / s;
    }
  }

  ln_kernel<<<M_, 64, 0, stream>>>(x, ln_g, ln_b, xn);
  qkv_kernel<<<dim3(15, 128), 256, 0, stream>>>(xn, qkv_w, qkv_b, q, k, vt);
  qk_kernel<<<dim3(8, 8, B_*H_), 256, 0, stream>>>(q, k, attn);
  bsp_kernel<<<dim3(N_/TM, B_*H_), 1024, 0, stream>>>(attn, vt, ao, gw);
  proj_kernel<<<dim3(5, 128), 256, 0, stream>>>(ao, proj_w, proj_b, out);
}